// Round 1
// baseline (3123.565 us; speedup 1.0000x reference)
//
#include <hip/hip_runtime.h>

#define HDIM 32

static constexpr int NU   = 500000;
static constexpr int NPOI = 200000;
static constexpr int NC   = 100;
static constexpr int E_UP = 500000;
static constexpr int E_PP = 1000000;

// ---------------------------------------------------------------------------
// zero scratch (grid-stride)
__global__ void zero_kernel(float* __restrict__ p, int n) {
    int i = blockIdx.x * blockDim.x + threadIdx.x;
    int stride = gridDim.x * blockDim.x;
    for (; i < n; i += stride) p[i] = 0.0f;
}

// ---------------------------------------------------------------------------
// h[i,f] = relu(sum_k x[i,k] * W[k,f] + b[f]) (+ emb[i,f])
// one thread per (node, feature)
__global__ void init_nodes(const float* __restrict__ x, int fin,
                           const float* __restrict__ W, const float* __restrict__ b,
                           const float* __restrict__ emb,
                           float* __restrict__ h, int n) {
    int idx = blockIdx.x * blockDim.x + threadIdx.x;
    if (idx >= n * HDIM) return;
    int i = idx >> 5, f = idx & 31;
    float r = b[f];
    for (int k = 0; k < fin; ++k) r += x[i * fin + k] * W[k * HDIM + f];
    r = fmaxf(r, 0.0f);
    if (emb) r += emb[idx];
    h[idx] = r;
}

// ---------------------------------------------------------------------------
// For each edge e: A[dst] += ea_e * src_h[src]  (32 floats, 32 lanes/edge)
//                  tc[dst] += (ea_e, 1)
__global__ void edge_scatter(const float* __restrict__ src_h,
                             const int* __restrict__ ei,
                             const float* __restrict__ ea,
                             float* __restrict__ A, float* __restrict__ tc, int E) {
    int gid = blockIdx.x * blockDim.x + threadIdx.x;
    int e = gid >> 5;
    if (e >= E) return;
    int f = gid & 31;
    int s = ei[e];       // ei[0,:] = src
    int d = ei[E + e];   // ei[1,:] = dst
    float w = ea ? ea[e] : 1.0f;
    unsafeAtomicAdd(&A[d * HDIM + f], src_h[s * HDIM + f] * w);
    if (f == 0) {
        unsafeAtomicAdd(&tc[2 * d + 0], w);
        unsafeAtomicAdd(&tc[2 * d + 1], 1.0f);
    }
}

// ---------------------------------------------------------------------------
// For each node d: r = (A[d] @ W + t*b) / max(c,1); dst[d] += relu(r)
// 32 lanes per node; A-row broadcast via __shfl within the 32-group.
// Also restores A/tc to zero for the next prop (saves 16 memsets).
__global__ void node_apply(float* __restrict__ dst_h, float* __restrict__ A,
                           float* __restrict__ tc,
                           const float* __restrict__ W, const float* __restrict__ b,
                           int n) {
    __shared__ float Ws[HDIM * HDIM];
    for (int i = threadIdx.x; i < HDIM * HDIM; i += blockDim.x) Ws[i] = W[i];
    __syncthreads();
    int idx = blockIdx.x * blockDim.x + threadIdx.x;
    int d = idx >> 5;
    if (d >= n) return;
    int f = idx & 31;
    float a = A[idx];
    A[idx] = 0.0f;                       // restore zero for next prop
    float t = tc[2 * d + 0];
    float c = tc[2 * d + 1];
    if (f == 0) { tc[2 * d + 0] = 0.0f; tc[2 * d + 1] = 0.0f; }
    float r = t * b[f];
#pragma unroll
    for (int k = 0; k < HDIM; ++k)
        r += __shfl(a, k, 32) * Ws[k * HDIM + f];
    r /= fmaxf(c, 1.0f);
    dst_h[idx] += fmaxf(r, 0.0f);
}

// ---------------------------------------------------------------------------
extern "C" void kernel_launch(void* const* d_in, const int* in_sizes, int n_in,
                              void* d_out, int out_size, void* d_ws, size_t ws_size,
                              hipStream_t stream) {
    const float* x_user = (const float*)d_in[0];
    const float* x_poi  = (const float*)d_in[1];
    const float* x_cate = (const float*)d_in[2];
    const float* ulw    = (const float*)d_in[3];
    const float* ulb    = (const float*)d_in[4];
    const float* plw    = (const float*)d_in[5];
    const float* plb    = (const float*)d_in[6];
    const float* clw    = (const float*)d_in[7];
    const float* clb    = (const float*)d_in[8];
    const float* W1u_w  = (const float*)d_in[9];   const float* W1u_b  = (const float*)d_in[10];
    const float* W1p_w  = (const float*)d_in[11];  const float* W1p_b  = (const float*)d_in[12];
    const float* W1c_w  = (const float*)d_in[13];  const float* W1c_b  = (const float*)d_in[14];
    const float* W1pp_w = (const float*)d_in[15];  const float* W1pp_b = (const float*)d_in[16];
    const float* W2u_w  = (const float*)d_in[17];  const float* W2u_b  = (const float*)d_in[18];
    const float* W2p_w  = (const float*)d_in[19];  const float* W2p_b  = (const float*)d_in[20];
    const float* W2c_w  = (const float*)d_in[21];  const float* W2c_b  = (const float*)d_in[22];
    const float* W2pp_w = (const float*)d_in[23];  const float* W2pp_b = (const float*)d_in[24];
    const float* cate_emb = (const float*)d_in[25];
    const int* ei_pv        = (const int*)d_in[26];
    const int* ei_mc        = (const int*)d_in[27];
    const int* ei_order     = (const int*)d_in[28];
    const int* ei_rev_pv    = (const int*)d_in[29];
    const int* ei_rev_mc    = (const int*)d_in[30];
    const int* ei_rev_order = (const int*)d_in[31];
    const int* ei_belongs   = (const int*)d_in[32];
    const int* ei_pp        = (const int*)d_in[33];
    const float* ea_pv        = (const float*)d_in[34];
    const float* ea_mc        = (const float*)d_in[35];
    const float* ea_order     = (const float*)d_in[36];
    const float* ea_rev_pv    = (const float*)d_in[37];
    const float* ea_rev_mc    = (const float*)d_in[38];
    const float* ea_rev_order = (const float*)d_in[39];
    const float* ea_pp        = (const float*)d_in[40];

    float* user_h = (float*)d_out;
    float* poi_h  = user_h + (size_t)NU * HDIM;
    float* cate_h = poi_h + (size_t)NPOI * HDIM;

    float* A  = (float*)d_ws;                 // [NU,32] accumulator (max dst count)
    float* tc = A + (size_t)NU * HDIM;        // [NU,2]  (sum_ea, count)

    // zero A+tc (contiguous) once; node_apply restores zeros thereafter
    int zn = NU * HDIM + NU * 2;
    hipLaunchKernelGGL(zero_kernel, dim3(2048), dim3(256), 0, stream, A, zn);

    hipLaunchKernelGGL(init_nodes, dim3((NU * HDIM + 255) / 256), dim3(256), 0, stream,
                       x_user, 2, ulw, ulb, (const float*)nullptr, user_h, NU);
    hipLaunchKernelGGL(init_nodes, dim3((NPOI * HDIM + 255) / 256), dim3(256), 0, stream,
                       x_poi, 3, plw, plb, (const float*)nullptr, poi_h, NPOI);
    hipLaunchKernelGGL(init_nodes, dim3((NC * HDIM + 255) / 256), dim3(256), 0, stream,
                       x_cate, 1, clw, clb, cate_emb, cate_h, NC);

    auto prop = [&](const float* src, const int* ei, const float* ea, int E,
                    const float* W, const float* b, float* dst, int n) {
        hipLaunchKernelGGL(edge_scatter, dim3((E * 32 + 255) / 256), dim3(256), 0, stream,
                           src, ei, ea, A, tc, E);
        hipLaunchKernelGGL(node_apply, dim3((n * 32 + 255) / 256), dim3(256), 0, stream,
                           dst, A, tc, W, b, n);
    };

    // ---- layer 1 ----
    prop(poi_h,  ei_rev_pv,    ea_rev_pv,    E_UP, W1p_w,  W1p_b,  user_h, NU);
    prop(poi_h,  ei_rev_mc,    ea_rev_mc,    E_UP, W1p_w,  W1p_b,  user_h, NU);
    prop(poi_h,  ei_rev_order, ea_rev_order, E_UP, W1p_w,  W1p_b,  user_h, NU);
    prop(user_h, ei_pv,        ea_pv,        E_UP, W1u_w,  W1u_b,  poi_h,  NPOI);
    prop(user_h, ei_mc,        ea_mc,        E_UP, W1u_w,  W1u_b,  poi_h,  NPOI);
    prop(user_h, ei_order,     ea_order,     E_UP, W1u_w,  W1u_b,  poi_h,  NPOI);
    prop(cate_h, ei_belongs,   nullptr,      NPOI, W1c_w,  W1c_b,  poi_h,  NPOI);
    prop(poi_h,  ei_pp,        ea_pp,        E_PP, W1pp_w, W1pp_b, poi_h,  NPOI);
    // ---- layer 2 ----
    prop(poi_h,  ei_rev_pv,    ea_rev_pv,    E_UP, W2p_w,  W2p_b,  user_h, NU);
    prop(poi_h,  ei_rev_mc,    ea_rev_mc,    E_UP, W2p_w,  W2p_b,  user_h, NU);
    prop(poi_h,  ei_rev_order, ea_rev_order, E_UP, W2p_w,  W2p_b,  user_h, NU);
    prop(user_h, ei_pv,        ea_pv,        E_UP, W2u_w,  W2u_b,  poi_h,  NPOI);
    prop(user_h, ei_mc,        ea_mc,        E_UP, W2u_w,  W2u_b,  poi_h,  NPOI);
    prop(user_h, ei_order,     ea_order,     E_UP, W2u_w,  W2u_b,  poi_h,  NPOI);
    prop(cate_h, ei_belongs,   nullptr,      NPOI, W2c_w,  W2c_b,  poi_h,  NPOI);
    prop(poi_h,  ei_pp,        ea_pp,        E_PP, W2pp_w, W2pp_b, poi_h,  NPOI);
}